// Round 9
// baseline (173.802 us; speedup 1.0000x reference)
//
#include <hip/hip_runtime.h>

#define BB 4096
#define TT 512
#define KK 7
#define SS0 256          // alpha-covered prefix; valid because len >= T/2 = 256
#define NCM 8            // matrix chunks
#define SSM 32           // steps per matrix chunk
#define NMAT (BB * NCM * KK)   // 229376 matrix-row threads
#define NALF (BB * 8)          // 32768 alpha lanes (8 per sequence)

__device__ __forceinline__ float fexp2(float x){ float r; asm("v_exp_f32 %0, %1" : "=v"(r) : "v"(x)); return r; }
__device__ __forceinline__ float flog2(float x){ float r; asm("v_log_f32 %0, %1" : "=v"(r) : "v"(x)); return r; }
__device__ __forceinline__ float uni(float x){ return __int_as_float(__builtin_amdgcn_readfirstlane(__float_as_int(x))); }

// ---------- p0: len[b] from prefix mask; e2 table ----------
__global__ __launch_bounds__(256) void crf_len(
    const int* __restrict__ msk, const float* __restrict__ trn,
    int* __restrict__ wlen, float* __restrict__ wse2)
{
  const float L2E = 1.44269504088896340736f;
  if (blockIdx.x == 0 && threadIdx.x < 49)
    wse2[threadIdx.x] = fexp2(trn[threadIdx.x] * L2E);
  int gid = blockIdx.x * 256 + threadIdx.x;
  int b = gid >> 6, lane = gid & 63;
  int4 a = *(const int4*)(msk + b * TT + lane * 8);
  int4 c = *(const int4*)(msk + b * TT + lane * 8 + 4);
  int s = a.x + a.y + a.z + a.w + c.x + c.y + c.z + c.w;
  #pragma unroll
  for (int o = 1; o < 64; o <<= 1) s += __shfl_xor(s, o);
  if (lane == 0) wlen[b] = s;
}

__device__ __forceinline__ void loadg(float* B, const float* ep, int g){
  #pragma unroll
  for (int p = 0; p < 7; p++){
    float4 f = *(const float4*)(ep + g * 28 + 4 * p);
    B[4*p] = f.x; B[4*p+1] = f.y; B[4*p+2] = f.z; B[4*p+3] = f.w;
  }
}

// 4 guarded steps of the row recurrence R' = (R @ E2) * 2^em
__device__ __forceinline__ void step4m(float* R, float& Lr, const float* E,
                                       int base, int a, const float* e2){
  const float L2E = 1.44269504088896340736f;
  #pragma unroll
  for (int s = 0; s < 4; s++){
    if (base + s < a){
      float acc[KK];
      #pragma unroll
      for (int j = 0; j < KK; j++) acc[j] = R[0] * e2[j];
      #pragma unroll
      for (int k = 1; k < KK; k++)
        #pragma unroll
        for (int j = 0; j < KK; j++) acc[j] = fmaf(R[k], e2[k*KK + j], acc[j]);
      #pragma unroll
      for (int j = 0; j < KK; j++) R[j] = acc[j] * fexp2(E[s*KK + j] * L2E);
    }
  }
  if (base + 3 < a){                 // exact pow2 renorm after a full group
    float mm = R[0];
    #pragma unroll
    for (int j = 1; j < KK; j++) mm = fmaxf(mm, R[j]);
    int ex = (int)((__float_as_uint(mm) >> 23) & 255) - 127;
    float scl = __uint_as_float((unsigned)(127 - ex) << 23);
    Lr += (float)ex;
    #pragma unroll
    for (int j = 0; j < KK; j++) R[j] *= scl;
  }
}

// one alpha step for lane owning state j: u' = (sum_k u_k e2[k][j]) * 2^em_j
__device__ __forceinline__ float astep(float u, float e, const float* e2c, int base){
  float g = fexp2(e * 1.44269504088896340736f);
  float acc = __shfl(u, base) * e2c[0];
  #pragma unroll
  for (int k = 1; k < KK; k++) acc = fmaf(__shfl(u, base + k), e2c[k], acc);
  return acc * g;
}

__device__ __forceinline__ float arenorm(float u, float& Ls){
  float m = u;
  m = fmaxf(m, __shfl_xor(m, 1));
  m = fmaxf(m, __shfl_xor(m, 2));
  m = fmaxf(m, __shfl_xor(m, 4));
  int ex = (int)((__float_as_uint(m) >> 23) & 255) - 127;
  float scl = __uint_as_float((unsigned)(127 - ex) << 23);
  Ls += (float)ex;
  return u * scl;
}

// ---------- p1: blocks 0..895 -> matrix rows (t=256..511); blocks 896..1023 -> alpha (t=0..255)
__global__ __launch_bounds__(256) void crf_p1(
    const float* __restrict__ em, const int* __restrict__ wlen,
    const float* __restrict__ wse2, const float* __restrict__ stt,
    float* __restrict__ wsA, float* __restrict__ wsP)
{
  const float L2E = 1.44269504088896340736f;
  int tid = blockIdx.x * 256 + threadIdx.x;

  if (tid < NMAT) {
    // ---- matrix-row chunk: thread = (c 0..7, row i 0..6, b) ----
    float e2[49];
    #pragma unroll
    for (int i = 0; i < 49; i++) e2[i] = uni(wse2[i]);
    int q = tid >> 12;                 // 0..55 = c*7 + i
    int b = tid & (BB - 1);
    int c = q / 7, i = q - c * 7;
    int t0 = SS0 + c * SSM;
    int a = wlen[b] - t0; a = a > SSM ? SSM : a;
    if (a > 0) {
      const float* ep = em + (size_t)b * (TT * KK) + (size_t)t0 * KK;
      float R[KK];
      #pragma unroll
      for (int j = 0; j < KK; j++) R[j] = (j == i) ? 1.f : 0.f;
      float Lr = 0.f;
      float bufA[28], bufB[28];
      loadg(bufA, ep, 0);
      if (a > 4) loadg(bufB, ep, 1);
      #pragma unroll
      for (int m = 0; m < 4; m++) {
        step4m(R, Lr, bufA, 8*m, a, e2);
        if (8*m + 8 < a)  loadg(bufA, ep, 2*m + 2);
        step4m(R, Lr, bufB, 8*m + 4, a, e2);
        if (8*m + 12 < a) loadg(bufB, ep, 2*m + 3);
      }
      float* P = wsP + ((size_t)c * BB + b) * 49 + i * KK;
      #pragma unroll
      for (int j = 0; j < KK; j++) P[j] = Lr + flog2(R[j]);
    }
  } else {
    // ---- alpha scan, wave-parallel: 8 lanes per b, lane j owns state j ----
    int atid = tid - NMAT;
    int lane = atid & 63;
    int jj = lane & 7;
    int jeff = jj < 7 ? jj : 6;        // lane 7 mirrors state 6 (never read)
    int b = ((atid >> 6) << 3) + (lane >> 3);
    int base = lane & ~7;
    const float* ep = em + (size_t)b * (TT * KK);
    float e2c[KK];
    #pragma unroll
    for (int k = 0; k < KK; k++) e2c[k] = wse2[k * KK + jeff];
    float bA[4], bB[4];
    #pragma unroll
    for (int s = 0; s < 4; s++) bA[s] = ep[s * KK + jeff];
    #pragma unroll
    for (int s = 0; s < 4; s++) bB[s] = ep[(4 + s) * KK + jeff];
    // init t=0
    float a2 = (stt[jeff] + bA[0]) * L2E;
    float mm = a2;
    mm = fmaxf(mm, __shfl_xor(mm, 1));
    mm = fmaxf(mm, __shfl_xor(mm, 2));
    mm = fmaxf(mm, __shfl_xor(mm, 4));
    float u = fexp2(a2 - mm);
    float Ls = mm;
    #pragma unroll
    for (int s = 1; s < 4; s++) u = astep(u, bA[s], e2c, base);
    u = arenorm(u, Ls);
    // steady state: compute G(2m+1) from bB, G(2m+2) from bA; prefetch ahead
    for (int m = 0; m < 31; m++) {
      int tA = 8 * m + 8;
      #pragma unroll
      for (int s = 0; s < 4; s++) bA[s] = ep[(tA + s) * KK + jeff];
      #pragma unroll
      for (int s = 0; s < 4; s++) u = astep(u, bB[s], e2c, base);
      u = arenorm(u, Ls);
      int tB = 8 * m + 12;
      #pragma unroll
      for (int s = 0; s < 4; s++) bB[s] = ep[(tB + s) * KK + jeff];
      #pragma unroll
      for (int s = 0; s < 4; s++) u = astep(u, bA[s], e2c, base);
      u = arenorm(u, Ls);
    }
    #pragma unroll
    for (int s = 0; s < 4; s++) u = astep(u, bB[s], e2c, base);   // G63: t=252..255
    u = arenorm(u, Ls);
    if (jj < 7) wsA[b * 8 + jj] = Ls + flog2(u);
  }
}

// ---------- p2: one wave per b ----------
__global__ __launch_bounds__(256) void crf_p2(
    const float* __restrict__ em, const int* __restrict__ tgs,
    const float* __restrict__ trn, const float* __restrict__ stt,
    const float* __restrict__ ent, const float* __restrict__ wsA,
    const float* __restrict__ wsP, const int* __restrict__ wlen,
    float* __restrict__ out)
{
  const float L2E = 1.44269504088896340736f;
  const float LN2 = 0.69314718055994530942f;
  __shared__ float sm[4];
  int w = threadIdx.x >> 6, lane = threadIdx.x & 63;
  int b = blockIdx.x * 4 + w;
  const int* trow = tgs + b * TT;
  const size_t eb = (size_t)b * (TT * KK);
  int len = wlen[b];

  // tag-path score, t-parallel (lane l owns t = l*8 .. l*8+7)
  int4 ta = *(const int4*)(trow + lane * 8);
  int4 tb = *(const int4*)(trow + lane * 8 + 4);
  int tga[8] = {ta.x, ta.y, ta.z, ta.w, tb.x, tb.y, tb.z, tb.w};
  int tprev = lane ? trow[lane * 8 - 1] : 0;
  float scp = 0.f;
  #pragma unroll
  for (int s = 0; s < 8; s++) {
    int t = lane * 8 + s; int tg = tga[s];
    if (t == 0)          scp += stt[tg] + em[eb + tg];
    else if (t < len)    scp += trn[tprev * KK + tg] + em[eb + (size_t)t * KK + tg];
    if (t == len - 1)    scp += ent[tg];
    tprev = tg;
  }
  float score = scp;
  #pragma unroll
  for (int o = 1; o < 64; o <<= 1) score += __shfl_xor(score, o);

  // combine matrix-chunk maps (lane j owns state j; depth-2 prefetch; chain <= 8)
  float A = (lane < KK) ? wsA[b * 8 + lane] : -1e30f;
  int j = (lane < KK) ? lane : 0;
  int nact = (len > SS0) ? ((len - SS0 + SSM - 1) >> 5) : 0;
  const float* Pb = wsP + (size_t)b * 49;
  const size_t cs = (size_t)BB * 49;
  float cur[KK];
  if (nact >= 1) {
    #pragma unroll
    for (int i = 0; i < KK; i++) cur[i] = Pb[i * KK + j];
  }
  for (int c2 = 0; c2 < nact; c2++) {
    float nxt[KK];
    if (c2 + 1 < nact) {
      #pragma unroll
      for (int i = 0; i < KK; i++) nxt[i] = Pb[(size_t)(c2 + 1) * cs + i * KK + j];
    }
    float v[KK];
    #pragma unroll
    for (int i = 0; i < KK; i++) v[i] = __shfl(A, i) + cur[i];
    float m = v[0];
    #pragma unroll
    for (int i = 1; i < KK; i++) m = fmaxf(m, v[i]);
    float ssum = 0.f;
    #pragma unroll
    for (int i = 0; i < KK; i++) ssum += fexp2(v[i] - m);
    A = m + flog2(ssum);
    #pragma unroll
    for (int i = 0; i < KK; i++) cur[i] = nxt[i];
  }

  float x = (lane < KK) ? A + ent[lane] * L2E : -1e30f;
  float mx = x;
  #pragma unroll
  for (int o = 1; o < 8; o <<= 1) mx = fmaxf(mx, __shfl_xor(mx, o));
  float se = fexp2(x - mx);
  #pragma unroll
  for (int o = 1; o < 8; o <<= 1) se += __shfl_xor(se, o);

  if (lane == 0) {
    float logz = LN2 * (mx + flog2(se));
    sm[w] = (logz - score) * (1.0f / BB);
  }
  __syncthreads();
  if (threadIdx.x == 0) atomicAdd(out, sm[0] + sm[1] + sm[2] + sm[3]);
}

extern "C" void kernel_launch(void* const* d_in, const int* in_sizes, int n_in,
                              void* d_out, int out_size, void* d_ws, size_t ws_size,
                              hipStream_t stream) {
  const float* em  = (const float*)d_in[0];
  const int*   msk = (const int*)d_in[1];
  const int*   tgs = (const int*)d_in[2];
  const float* trn = (const float*)d_in[3];
  const float* stt = (const float*)d_in[4];
  const float* ent = (const float*)d_in[5];
  float* out = (float*)d_out;

  float* wsA  = (float*)d_ws;                          // BB*8
  float* wsP  = wsA + (size_t)BB * 8;                  // NCM*BB*49
  float* wse2 = wsP + (size_t)NCM * BB * 49;           // 64
  int*   wlen = (int*)(wse2 + 64);                     // BB

  hipMemsetAsync(out, 0, sizeof(float), stream);
  hipLaunchKernelGGL(crf_len, dim3(BB * 64 / 256), dim3(256), 0, stream,
                     msk, trn, wlen, wse2);
  hipLaunchKernelGGL(crf_p1, dim3((NMAT + NALF) / 256), dim3(256), 0, stream,
                     em, wlen, wse2, stt, wsA, wsP);
  hipLaunchKernelGGL(crf_p2, dim3(BB / 4), dim3(256), 0, stream,
                     em, tgs, trn, stt, ent, wsA, wsP, wlen, out);
}